// Round 1
// baseline (601.082 us; speedup 1.0000x reference)
//
#include <hip/hip_runtime.h>
#include <math.h>

#define NB    2048
#define NTOK  49
#define CH    768
#define MID   48
#define K1    36
#define K2    24
#define NTHR  512
#define NWAVE (NTHR/64)

__device__ __forceinline__ float wsum(float v) {
    #pragma unroll
    for (int off = 32; off; off >>= 1) v += __shfl_xor(v, off, 64);
    return v;
}

__global__ __launch_bounds__(NTHR, 2)
void hier_se_fused(const float* __restrict__ x,
                   const float* __restrict__ w1a, const float* __restrict__ b1a,
                   const float* __restrict__ w2a, const float* __restrict__ b2a,
                   const float* __restrict__ w1b, const float* __restrict__ b1b,
                   const float* __restrict__ w2b, const float* __restrict__ b2b,
                   const float* __restrict__ lng, const float* __restrict__ lnb,
                   const float* __restrict__ cw,  const float* __restrict__ cb,
                   float* __restrict__ out)
{
    // ~158 KB of LDS: whole 49x768 fp32 tile resident per block (1 block/CU).
    __shared__ __align__(16) float tok[NTOK*CH];   // 150528 B
    __shared__ float sA[CH];        // s / s2 / pooled (reused)
    __shared__ float g1[CH];        // round-1 gates
    __shared__ float g12[CH];       // g1*g2
    __shared__ float hb[MID];       // GEMV hidden
    __shared__ float red[NWAVE*MID];// cross-wave GEMV partials
    __shared__ float ts[64];        // row scores (norms)
    __shared__ int   sel1[K1];
    __shared__ int   sel2[K2];
    __shared__ float scal[2];       // LN mu, inv_std

    const int tid  = threadIdx.x;
    const int lane = tid & 63;
    const int wv   = tid >> 6;
    const int b    = blockIdx.x;

    // ---- P0: stage x[b] tile into LDS (coalesced float4), and prefetch the
    //          round-1 w1 slice into registers so its L2 latency hides under
    //          the HBM tile load.
    {
        const float4* src = (const float4*)(x + (size_t)b * (NTOK*CH));
        float4* dst = (float4*)tok;
        #pragma unroll
        for (int k = 0; k < 19; ++k) {
            int i = k*NTHR + tid;
            if (i < NTOK*CH/4) dst[i] = src[i];
        }
    }
    // wave wv owns c in [96*wv, 96*wv+96); lane l (<48) owns output m=l.
    float wreg[96];
    {
        const int ml = lane < MID ? lane : MID-1;   // lanes 48..63: dup, unused
        const float* wp = w1a + (96*wv)*MID + ml;
        #pragma unroll
        for (int k = 0; k < 96; ++k) wreg[k] = wp[k*MID];
    }
    __syncthreads();

    // ---- P1: column means s = mean_n x[b,n,:]  -> sA
    for (int c = tid; c < CH; c += NTHR) {
        float a0 = tok[48*CH + c], a1 = 0.f;
        #pragma unroll
        for (int n = 0; n < 48; n += 2) { a0 += tok[n*CH+c]; a1 += tok[(n+1)*CH+c]; }
        sA[c] = (a0 + a1) * (1.0f/NTOK);
    }
    __syncthreads();

    // ---- P2: partials of h = s @ w1a (per-wave c-slice, lane = m)
    {
        float a0=0.f,a1=0.f,a2=0.f,a3=0.f;
        #pragma unroll
        for (int k = 0; k < 96; k += 4) {
            a0 = fmaf(wreg[k+0], sA[96*wv+k+0], a0);
            a1 = fmaf(wreg[k+1], sA[96*wv+k+1], a1);
            a2 = fmaf(wreg[k+2], sA[96*wv+k+2], a2);
            a3 = fmaf(wreg[k+3], sA[96*wv+k+3], a3);
        }
        if (lane < MID) red[wv*MID + lane] = (a0+a1)+(a2+a3);
    }
    // prefetch round-2 w1 into the now-dead wreg (overlaps P3..P6 compute)
    {
        const int ml = lane < MID ? lane : MID-1;
        const float* wp = w1b + (96*wv)*MID + ml;
        #pragma unroll
        for (int k = 0; k < 96; ++k) wreg[k] = wp[k*MID];
    }
    __syncthreads();
    if (tid < MID) {
        float v = b1a[tid];
        #pragma unroll
        for (int w = 0; w < NWAVE; ++w) v += red[w*MID + tid];
        hb[tid] = 0.5f * v * (1.0f + erff(v * 0.70710678118654752440f)); // exact gelu
    }
    __syncthreads();

    // ---- P3: gates1 = sigmoid(h @ w2a + b2a)
    for (int c = tid; c < CH; c += NTHR) {
        float a0=0.f,a1=0.f,a2=0.f,a3=0.f;
        #pragma unroll
        for (int m = 0; m < MID; m += 4) {
            a0 = fmaf(hb[m+0], w2a[(m+0)*CH + c], a0);
            a1 = fmaf(hb[m+1], w2a[(m+1)*CH + c], a1);
            a2 = fmaf(hb[m+2], w2a[(m+2)*CH + c], a2);
            a3 = fmaf(hb[m+3], w2a[(m+3)*CH + c], a3);
        }
        float v = b2a[c] + ((a0+a1)+(a2+a3));
        g1[c] = 1.0f / (1.0f + expf(-v));
    }
    __syncthreads();

    // ---- P4: ts[n] = || x[b,n,:] * g1 ||_2   (one row per wave-iteration)
    for (int n = wv; n < NTOK; n += NWAVE) {
        float acc = 0.f;
        #pragma unroll
        for (int k = 0; k < CH/64; ++k) {
            int c = lane + k*64;
            float v = tok[n*CH + c] * g1[c];
            acc = fmaf(v, v, acc);
        }
        acc = wsum(acc);
        if (lane == 0) ts[n] = sqrtf(acc);
    }
    __syncthreads();

    // ---- P5: top-36 of ts (softmax((ts-mean)/std) is monotone in ts, so
    //          ranking ts reproduces top_k(importance) incl. tie-breaks).
    if (wv == 0) {
        float vl = (lane < NTOK) ? ts[lane] : -1.0f;
        int rank = 0;
        for (int j = 0; j < NTOK; ++j) {
            float vj = ts[j];
            rank += (vj > vl) || (vj == vl && j < lane);
        }
        if (lane < NTOK && rank < K1) sel1[rank] = lane;  // rank order = jax top_k order
    }
    __syncthreads();

    // ---- P6: s2 = mean over selected of (x*g1) = g1 * mean(selected rows)
    {
        int rows[K1];
        #pragma unroll
        for (int r = 0; r < K1; ++r) rows[r] = sel1[r]*CH;
        for (int c = tid; c < CH; c += NTHR) {
            float a0=0.f,a1=0.f;
            #pragma unroll
            for (int r = 0; r < K1; r += 2) { a0 += tok[rows[r]+c]; a1 += tok[rows[r+1]+c]; }
            sA[c] = (a0+a1) * (1.0f/K1) * g1[c];
        }
    }
    __syncthreads();

    // ---- P7: h2 = gelu(s2 @ w1b + b1b)  (wreg holds w1b)
    {
        float a0=0.f,a1=0.f,a2=0.f,a3=0.f;
        #pragma unroll
        for (int k = 0; k < 96; k += 4) {
            a0 = fmaf(wreg[k+0], sA[96*wv+k+0], a0);
            a1 = fmaf(wreg[k+1], sA[96*wv+k+1], a1);
            a2 = fmaf(wreg[k+2], sA[96*wv+k+2], a2);
            a3 = fmaf(wreg[k+3], sA[96*wv+k+3], a3);
        }
        if (lane < MID) red[wv*MID + lane] = (a0+a1)+(a2+a3);
    }
    __syncthreads();
    if (tid < MID) {
        float v = b1b[tid];
        #pragma unroll
        for (int w = 0; w < NWAVE; ++w) v += red[w*MID + tid];
        hb[tid] = 0.5f * v * (1.0f + erff(v * 0.70710678118654752440f));
    }
    __syncthreads();

    // ---- P8: g12 = g1 * sigmoid(h2 @ w2b + b2b)
    for (int c = tid; c < CH; c += NTHR) {
        float a0=0.f,a1=0.f,a2=0.f,a3=0.f;
        #pragma unroll
        for (int m = 0; m < MID; m += 4) {
            a0 = fmaf(hb[m+0], w2b[(m+0)*CH + c], a0);
            a1 = fmaf(hb[m+1], w2b[(m+1)*CH + c], a1);
            a2 = fmaf(hb[m+2], w2b[(m+2)*CH + c], a2);
            a3 = fmaf(hb[m+3], w2b[(m+3)*CH + c], a3);
        }
        float v = b2b[c] + ((a0+a1)+(a2+a3));
        g12[c] = g1[c] * (1.0f / (1.0f + expf(-v)));
    }
    __syncthreads();

    // ---- P9: ts2[j] = || x[row_j] * g12 ||  (j indexes round-1 rank order)
    for (int j = wv; j < K1; j += NWAVE) {
        int base = sel1[j]*CH;
        float acc = 0.f;
        #pragma unroll
        for (int k = 0; k < CH/64; ++k) {
            int c = lane + k*64;
            float v = tok[base + c] * g12[c];
            acc = fmaf(v, v, acc);
        }
        acc = wsum(acc);
        if (lane == 0) ts[j] = sqrtf(acc);
    }
    __syncthreads();

    // ---- P10: top-24 of ts2 (tie-break by j = round-1 rank, matching ref)
    if (wv == 0) {
        float vl = (lane < K1) ? ts[lane] : -1.0f;
        int rank = 0;
        for (int j = 0; j < K1; ++j) {
            float vj = ts[j];
            rank += (vj > vl) || (vj == vl && j < lane);
        }
        if (lane < K1 && rank < K2) sel2[rank] = sel1[lane];
    }
    __syncthreads();

    // ---- P11: pooled = g12 * mean over final 24 rows
    {
        int rows[K2];
        #pragma unroll
        for (int r = 0; r < K2; ++r) rows[r] = sel2[r]*CH;
        for (int c = tid; c < CH; c += NTHR) {
            float a0=0.f,a1=0.f;
            #pragma unroll
            for (int r = 0; r < K2; r += 2) { a0 += tok[rows[r]+c]; a1 += tok[rows[r+1]+c]; }
            sA[c] = (a0+a1) * (1.0f/K2) * g12[c];
        }
    }
    __syncthreads();

    // ---- P12: LayerNorm stats (ddof=0 var, eps=1e-5)
    if (wv == 0) {
        float s = 0.f, q = 0.f;
        #pragma unroll
        for (int k = 0; k < CH/64; ++k) {
            float v = sA[lane + k*64];
            s += v; q = fmaf(v, v, q);
        }
        s = wsum(s); q = wsum(q);
        if (lane == 0) {
            float mu  = s * (1.0f/CH);
            float var = q * (1.0f/CH) - mu*mu;
            scal[0] = mu;
            scal[1] = rsqrtf(var + 1e-5f);
        }
    }
    __syncthreads();

    // ---- P13: out[b,k] = normed @ cls_w[:,k] + cls_b[k]  (wave k, k<5)
    if (wv < 5) {
        const float mu = scal[0], inv = scal[1];
        float acc = 0.f;
        #pragma unroll
        for (int k = 0; k < CH/64; ++k) {
            int c = lane + k*64;
            float nv = (sA[c] - mu) * inv * lng[c] + lnb[c];
            acc = fmaf(nv, cw[c*5 + wv], acc);
        }
        acc = wsum(acc);
        if (lane == 0) out[b*5 + wv] = acc + cb[wv];
    }
}

extern "C" void kernel_launch(void* const* d_in, const int* in_sizes, int n_in,
                              void* d_out, int out_size, void* d_ws, size_t ws_size,
                              hipStream_t stream) {
    (void)in_sizes; (void)n_in; (void)d_ws; (void)ws_size; (void)out_size;
    const float* x   = (const float*)d_in[0];
    const float* w1a = (const float*)d_in[1];
    const float* b1a = (const float*)d_in[2];
    const float* w2a = (const float*)d_in[3];
    const float* b2a = (const float*)d_in[4];
    const float* w1b = (const float*)d_in[5];
    const float* b1b = (const float*)d_in[6];
    const float* w2b = (const float*)d_in[7];
    const float* b2b = (const float*)d_in[8];
    const float* lng = (const float*)d_in[9];
    const float* lnb = (const float*)d_in[10];
    const float* cw  = (const float*)d_in[11];
    const float* cb  = (const float*)d_in[12];
    float* out = (float*)d_out;

    hipLaunchKernelGGL(hier_se_fused, dim3(NB), dim3(NTHR), 0, stream,
                       x, w1a, b1a, w2a, b2a, w1b, b1b, w2b, b2b,
                       lng, lnb, cw, cb, out);
}